// Round 11
// baseline (105.679 us; speedup 1.0000x reference)
//
#include <hip/hip_runtime.h>
#include <hip/hip_bf16.h>
#include <math.h>

#define NROWS 8192
#define DDIM  128
#define JCHUNKS 32
#define JPER  (NROWS / JCHUNKS)        // 256 cols per chunk
#define STAGE_COLS 64
#define NSTAGES (JPER / STAGE_COLS)    // 4
#define ROWS_PER_BLOCK 256             // 8 waves x 32 rows share one B-tile
#define GRIDX (NROWS / ROWS_PER_BLOCK) // 32 -> grid 32 x 32 = 1024 blocks = 4/CU
#define LOG2E 1.44269504088896f

#define AS1 __attribute__((address_space(1)))
#define AS3 __attribute__((address_space(3)))

typedef __attribute__((ext_vector_type(8))) short bf16x8;  // 8 bf16 = 4 VGPRs
typedef __attribute__((ext_vector_type(4))) float f32x4;

// ---------------- kernel 1: L2 row-normalize -> bf16 (also zeroes out[0]) ----------------
__global__ __launch_bounds__(256) void norm_kernel(
    const float* __restrict__ f1, const float* __restrict__ f2,
    __hip_bfloat16* __restrict__ f1b, __hip_bfloat16* __restrict__ f2b,
    float* __restrict__ out) {
  if (blockIdx.x == 0 && threadIdx.x == 0) out[0] = 0.0f;  // stream-ordered before finalize
  int t = threadIdx.x;
  int rloc = t >> 5;                 // 0..7
  int l = t & 31;
  int b = blockIdx.x;                // 0..2047
  int half = (b >= NROWS / 8) ? 1 : 0;
  int row = (b - half * (NROWS / 8)) * 8 + rloc;
  const float* src = half ? f2 : f1;
  __hip_bfloat16* dst = half ? f2b : f1b;

  float4 v = ((const float4*)src)[row * (DDIM / 4) + l];
  float s = v.x * v.x + v.y * v.y + v.z * v.z + v.w * v.w;
  #pragma unroll
  for (int off = 1; off < 32; off <<= 1) s += __shfl_xor(s, off, 64);
  float inv = 1.0f / fmaxf(sqrtf(s), 1e-12f);
  __hip_bfloat16 hv[4];
  hv[0] = __float2bfloat16(v.x * inv);
  hv[1] = __float2bfloat16(v.y * inv);
  hv[2] = __float2bfloat16(v.z * inv);
  hv[3] = __float2bfloat16(v.w * inv);
  *(ushort4*)&dst[(size_t)row * DDIM + l * 4] = *(ushort4*)hv;
}

// ---------------- kernel 2: MFMA cos grid — R5 body, 8 waves/SIMD ----------------
// Session synthesis: all staged variants ran at 4 waves/SIMD; every pipe <=35% busy ->
// latency-stall-bound. This config doubles TLP: 1024 blocks (4/CU) x 8 waves, VGPR
// forced to 64 via (512,4) (R5 proved this rs=2 body fits that cap cleanly), LDS
// 33.8KB x 4 blocks = 135KB. JCHUNKS=32 association order proven bit-exact in R9.
// partials[(row*JCHUNKS + chunk)*4 + {Z,Zp,Cp,Np}]
__global__ __launch_bounds__(512, 4) void stats_kernel(
    const __hip_bfloat16* __restrict__ f1b,
    const __hip_bfloat16* __restrict__ f2b,
    const float* __restrict__ targets,
    float* __restrict__ partials) {
  __shared__ __align__(16) char lds0[STAGE_COLS * 256];   // 16 KB
  __shared__ __align__(16) char lds1[STAGE_COLS * 256];   // 16 KB
  __shared__ __align__(16) float tsh[JPER];               // 1 KB

  const int chunk = blockIdx.y;                  // 0..31
  const int i0 = blockIdx.x * ROWS_PER_BLOCK;
  const int w    = threadIdx.x >> 6;             // 0..7
  const int lane = threadIdx.x & 63;
  const int p15  = lane & 15;
  const int rl4  = lane >> 4;                    // quad
  const int rbase = i0 + w * 32;                 // this wave's 32 rows

  // ---- A fragments resident for whole sweep: A[m=p15][k = rl4*8 + ks*32 ..] ----
  bf16x8 afrag[2][4];
  #pragma unroll
  for (int rs = 0; rs < 2; ++rs) {
    const __hip_bfloat16* arow =
        &f1b[(size_t)(rbase + rs * 16 + p15) * DDIM + rl4 * 8];
    #pragma unroll
    for (int ks = 0; ks < 4; ++ks)
      afrag[rs][ks] = *(const bf16x8*)(arow + ks * 32);
  }

  // lane's C rows per rs: row = rbase + rs*16 + rl4*4 + rr  (reg rr of acc)
  f32x4 ki[2];
  #pragma unroll
  for (int rs = 0; rs < 2; ++rs)
    #pragma unroll
    for (int rr = 0; rr < 4; ++rr)
      ki[rs][rr] = targets[rbase + rs * 16 + rl4 * 4 + rr];

  f32x4 Z[2], Zp[2], Cp[2], Np[2];
  #pragma unroll
  for (int rs = 0; rs < 2; ++rs) {
    Z[rs] = (f32x4){0.f, 0.f, 0.f, 0.f};
    Zp[rs] = (f32x4){0.f, 0.f, 0.f, 0.f};
    Cp[rs] = (f32x4){0.f, 0.f, 0.f, 0.f};
    Np[rs] = (f32x4){0.f, 0.f, 0.f, 0.f};
  }

  const int jb0 = chunk * JPER;

  // ---- DMA source offsets within a 64-row stage block (2 rounds x 512 lanes x 16B = 16 KB)
  // LDS[row][x] = global[row][x ^ (row & 15)]  (involution swizzle; read undoes it)
  int srcoff[2];
  #pragma unroll
  for (int q = 0; q < 2; ++q) {
    int rloc = w * 8 + q * 4 + rl4;            // 0..63, distinct over (w,q,rl4)
    int c    = p15 ^ (rloc & 15);
    srcoff[q] = rloc * DDIM + c * 8;
  }

  // prologue: DMA targets chunk (256 floats, waves 0..3) + stage 0 -> lds0
  {
    if (w < 4)
      __builtin_amdgcn_global_load_lds(
          (const AS1 void*)(targets + jb0 + w * 64 + lane),
          (AS3 void*)(&tsh[w * 64]), 4, 0, 0);
    const __hip_bfloat16* gstage = f2b + (size_t)jb0 * DDIM;
    char* lbase = &lds0[w * 2048];
    #pragma unroll
    for (int q = 0; q < 2; ++q)
      __builtin_amdgcn_global_load_lds((const AS1 void*)(gstage + srcoff[q]),
                                       (AS3 void*)(lbase + q * 1024), 16, 0, 0);
  }

  for (int s = 0; s < NSTAGES; ++s) {
    __syncthreads();   // stage-s DMA complete; buf[(s+1)&1] free to overwrite

    if (s + 1 < NSTAGES) {
      const __hip_bfloat16* gstage = f2b + (size_t)(jb0 + (s + 1) * STAGE_COLS) * DDIM;
      char* lbase = ((s + 1) & 1) ? &lds1[w * 2048] : &lds0[w * 2048];
      #pragma unroll
      for (int q = 0; q < 2; ++q)
        __builtin_amdgcn_global_load_lds((const AS1 void*)(gstage + srcoff[q]),
                                         (AS3 void*)(lbase + q * 1024), 16, 0, 0);
    }

    const char* lb = (s & 1) ? lds1 : lds0;
    #pragma unroll
    for (int ct = 0; ct < 4; ++ct) {
      const int rloc = ct * 16 + p15;            // B row (col index n) in stage; rloc&15 == p15
      bf16x8 bfrag[4];
      #pragma unroll
      for (int ks = 0; ks < 4; ++ks)
        bfrag[ks] = *(const bf16x8*)(lb + rloc * 256 + (((rl4 + ks * 4) ^ p15) << 4));

      float tj = tsh[s * STAGE_COLS + ct * 16 + p15];  // quad-broadcast: conflict-free
      const bool pj = tj > 0.0f;
      const f32x4 tj4 = {tj, tj, tj, tj};
      const f32x4 K4  = {LOG2E, LOG2E, LOG2E, LOG2E};

      #pragma unroll
      for (int rs = 0; rs < 2; ++rs) {
        f32x4 acc = {0.f, 0.f, 0.f, 0.f};
        #pragma unroll
        for (int ks = 0; ks < 4; ++ks)
          acc = __builtin_amdgcn_mfma_f32_16x16x32_bf16(afrag[rs][ks], bfrag[ks], acc, 0, 0, 0);

        f32x4 c4 = acc;
        f32x4 d4 = ki[rs] - tj4;
        f32x4 m4;
        #pragma unroll
        for (int rr = 0; rr < 4; ++rr) {
          bool q = (__builtin_fabsf(d4[rr]) <= 0.1f) & ((ki[rs][rr] > 0.0f) == pj);
          m4[rr] = q ? 1.0f : 0.0f;
        }
        f32x4 x4 = c4 * K4 - K4;
        f32x4 e4;
        #pragma unroll
        for (int rr = 0; rr < 4; ++rr) e4[rr] = __builtin_amdgcn_exp2f(x4[rr]);
        Z[rs]  += e4;
        Zp[rs] += m4 * e4;
        Cp[rs] += m4 * c4;
        Np[rs] += m4;
      }
    }
  }

  // reduce over the 16 lanes (p15) sharing each row
  #pragma unroll
  for (int rs = 0; rs < 2; ++rs) {
    #pragma unroll
    for (int rr = 0; rr < 4; ++rr) {
      #pragma unroll
      for (int off = 1; off < 16; off <<= 1) {
        Z[rs][rr]  += __shfl_xor(Z[rs][rr],  off, 64);
        Zp[rs][rr] += __shfl_xor(Zp[rs][rr], off, 64);
        Cp[rs][rr] += __shfl_xor(Cp[rs][rr], off, 64);
        Np[rs][rr] += __shfl_xor(Np[rs][rr], off, 64);
      }
    }
  }
  if (p15 == 0) {
    #pragma unroll
    for (int rs = 0; rs < 2; ++rs)
      #pragma unroll
      for (int rr = 0; rr < 4; ++rr) {
        size_t row = rbase + rs * 16 + rl4 * 4 + rr;
        f32x4 st = {Z[rs][rr], Zp[rs][rr], Cp[rs][rr], Np[rs][rr]};
        *(f32x4*)&partials[((size_t)row * JCHUNKS + chunk) * 4] = st;
      }
  }
}

// ---------------- kernel 3: per-row loss + global mean (atomic) ----------------
__global__ void finalize_rows(const float* __restrict__ partials,
                              float* __restrict__ out) {
  int r = blockIdx.x * 256 + threadIdx.x;   // grid 32 x 256
  float Z = 0, Zp = 0, Cp = 0, Np = 0;
  for (int ch = 0; ch < JCHUNKS; ++ch) {
    float4 p = *(const float4*)&partials[((size_t)r * JCHUNKS + ch) * 4];
    Z += p.x; Zp += p.y; Cp += p.z; Np += p.w;
  }
  float Zn = Z - Zp;
  float nn = (float)NROWS - Np;
  float spos = (1.0f + logf(Z)) - Cp / Np;
  float sneg = Zn / Z - nn * 1e-10f;
  float per_row = spos + sneg / nn;

  float v = per_row;
  for (int off = 32; off; off >>= 1) v += __shfl_xor(v, off, 64);
  __shared__ float wsum[4];
  int lane = threadIdx.x & 63, wid = threadIdx.x >> 6;
  if (lane == 0) wsum[wid] = v;
  __syncthreads();
  if (threadIdx.x == 0)
    atomicAdd(out, (wsum[0] + wsum[1] + wsum[2] + wsum[3]) * (1.0f / (float)NROWS));
}

// ---------------- launch ----------------
extern "C" void kernel_launch(void* const* d_in, const int* in_sizes, int n_in,
                              void* d_out, int out_size, void* d_ws, size_t ws_size,
                              hipStream_t stream) {
  const float* f1  = (const float*)d_in[0];
  const float* f2  = (const float*)d_in[1];
  const float* tgt = (const float*)d_in[2];
  float* out = (float*)d_out;

  char* ws = (char*)d_ws;
  __hip_bfloat16* f1b = (__hip_bfloat16*)ws;                       // 2 MB
  __hip_bfloat16* f2b = (__hip_bfloat16*)(ws + (size_t)NROWS * DDIM * 2);
  float* partials = (float*)(ws + (size_t)NROWS * DDIM * 4);       // 4 MB

  norm_kernel<<<2 * (NROWS / 8), 256, 0, stream>>>(f1, f2, f1b, f2b, out);
  dim3 g2(GRIDX, JCHUNKS);
  stats_kernel<<<g2, 512, 0, stream>>>(f1b, f2b, tgt, partials);
  finalize_rows<<<NROWS / 256, 256, 0, stream>>>(partials, out);
}

// Round 12
// 97.759 us; speedup vs baseline: 1.0810x; 1.0810x over previous
//
#include <hip/hip_runtime.h>
#include <hip/hip_bf16.h>
#include <math.h>

#define NROWS 8192
#define DDIM  128
#define JCHUNKS 16
#define JPER  (NROWS / JCHUNKS)        // 512 cols per chunk
#define STAGE_COLS 64
#define NSTAGES (JPER / STAGE_COLS)    // 8
#define ROWS_PER_BLOCK 256             // 8 waves x 32 rows share one B-tile
#define GRIDX (NROWS / ROWS_PER_BLOCK) // 32
#define LOG2E 1.44269504088896f

#define AS1 __attribute__((address_space(1)))
#define AS3 __attribute__((address_space(3)))

typedef __attribute__((ext_vector_type(8))) short bf16x8;  // 8 bf16 = 4 VGPRs
typedef __attribute__((ext_vector_type(4))) float f32x4;

// ---------------- kernel 1: L2 row-normalize -> bf16 (also zeroes out[0]) ----------------
__global__ __launch_bounds__(256) void norm_kernel(
    const float* __restrict__ f1, const float* __restrict__ f2,
    __hip_bfloat16* __restrict__ f1b, __hip_bfloat16* __restrict__ f2b,
    float* __restrict__ out) {
  if (blockIdx.x == 0 && threadIdx.x == 0) out[0] = 0.0f;  // stream-ordered before finalize
  int t = threadIdx.x;
  int rloc = t >> 5;                 // 0..7
  int l = t & 31;
  int b = blockIdx.x;                // 0..2047
  int half = (b >= NROWS / 8) ? 1 : 0;
  int row = (b - half * (NROWS / 8)) * 8 + rloc;
  const float* src = half ? f2 : f1;
  __hip_bfloat16* dst = half ? f2b : f1b;

  float4 v = ((const float4*)src)[row * (DDIM / 4) + l];
  float s = v.x * v.x + v.y * v.y + v.z * v.z + v.w * v.w;
  #pragma unroll
  for (int off = 1; off < 32; off <<= 1) s += __shfl_xor(s, off, 64);
  float inv = 1.0f / fmaxf(sqrtf(s), 1e-12f);
  __hip_bfloat16 hv[4];
  hv[0] = __float2bfloat16(v.x * inv);
  hv[1] = __float2bfloat16(v.y * inv);
  hv[2] = __float2bfloat16(v.z * inv);
  hv[3] = __float2bfloat16(v.w * inv);
  *(ushort4*)&dst[(size_t)row * DDIM + l * 4] = *(ushort4*)hv;
}

// ---------------- kernel 2: MFMA cos grid, LDS B-tile shared by 8 waves (256 rows) ----------------
// Session-best configuration (R5: dur 98.67us, absmax 0.0). 512-thr blocks: one 16 KB
// B-stage feeds 256 rows; rs=2 compute at VGPR 64 via (512,4). Falsification matrix
// (R6-R11): LDS volume, barrier count, occupancy, ILP, pk-pairing all neutral-or-worse
// -> this is the measured optimum of the structure family.
// partials[(row*JCHUNKS + chunk)*4 + {Z,Zp,Cp,Np}]
__global__ __launch_bounds__(512, 4) void stats_kernel(
    const __hip_bfloat16* __restrict__ f1b,
    const __hip_bfloat16* __restrict__ f2b,
    const float* __restrict__ targets,
    float* __restrict__ partials) {
  __shared__ __align__(16) char lds0[STAGE_COLS * 256];   // 16 KB
  __shared__ __align__(16) char lds1[STAGE_COLS * 256];   // 16 KB
  __shared__ __align__(16) float tsh[JPER];               // 2 KB

  const int chunk = blockIdx.y;                  // 0..15
  const int i0 = blockIdx.x * ROWS_PER_BLOCK;
  const int w    = threadIdx.x >> 6;             // 0..7
  const int lane = threadIdx.x & 63;
  const int p15  = lane & 15;
  const int rl4  = lane >> 4;                    // quad
  const int rbase = i0 + w * 32;                 // this wave's 32 rows

  // ---- A fragments resident for whole sweep: A[m=p15][k = rl4*8 + ks*32 ..] ----
  bf16x8 afrag[2][4];
  #pragma unroll
  for (int rs = 0; rs < 2; ++rs) {
    const __hip_bfloat16* arow =
        &f1b[(size_t)(rbase + rs * 16 + p15) * DDIM + rl4 * 8];
    #pragma unroll
    for (int ks = 0; ks < 4; ++ks)
      afrag[rs][ks] = *(const bf16x8*)(arow + ks * 32);
  }

  // lane's C rows per rs: row = rbase + rs*16 + rl4*4 + rr  (reg rr of acc)
  f32x4 ki[2];
  #pragma unroll
  for (int rs = 0; rs < 2; ++rs)
    #pragma unroll
    for (int rr = 0; rr < 4; ++rr)
      ki[rs][rr] = targets[rbase + rs * 16 + rl4 * 4 + rr];

  f32x4 Z[2], Zp[2], Cp[2], Np[2];
  #pragma unroll
  for (int rs = 0; rs < 2; ++rs) {
    Z[rs] = (f32x4){0.f, 0.f, 0.f, 0.f};
    Zp[rs] = (f32x4){0.f, 0.f, 0.f, 0.f};
    Cp[rs] = (f32x4){0.f, 0.f, 0.f, 0.f};
    Np[rs] = (f32x4){0.f, 0.f, 0.f, 0.f};
  }

  const int jb0 = chunk * JPER;

  // ---- DMA source offsets within a 64-row stage block (2 rounds x 512 lanes x 16B = 16 KB)
  // LDS[row][x] = global[row][x ^ (row & 15)]  (involution swizzle; read undoes it)
  int srcoff[2];
  #pragma unroll
  for (int q = 0; q < 2; ++q) {
    int rloc = w * 8 + q * 4 + rl4;            // 0..63, distinct over (w,q,rl4)
    int c    = p15 ^ (rloc & 15);
    srcoff[q] = rloc * DDIM + c * 8;
  }

  // prologue: DMA targets chunk (512 floats, 1 round) + stage 0 -> lds0
  {
    __builtin_amdgcn_global_load_lds(
        (const AS1 void*)(targets + jb0 + w * 64 + lane),
        (AS3 void*)(&tsh[w * 64]), 4, 0, 0);
    const __hip_bfloat16* gstage = f2b + (size_t)jb0 * DDIM;
    char* lbase = &lds0[w * 2048];
    #pragma unroll
    for (int q = 0; q < 2; ++q)
      __builtin_amdgcn_global_load_lds((const AS1 void*)(gstage + srcoff[q]),
                                       (AS3 void*)(lbase + q * 1024), 16, 0, 0);
  }

  for (int s = 0; s < NSTAGES; ++s) {
    __syncthreads();   // stage-s DMA complete; buf[(s+1)&1] free to overwrite

    if (s + 1 < NSTAGES) {
      const __hip_bfloat16* gstage = f2b + (size_t)(jb0 + (s + 1) * STAGE_COLS) * DDIM;
      char* lbase = ((s + 1) & 1) ? &lds1[w * 2048] : &lds0[w * 2048];
      #pragma unroll
      for (int q = 0; q < 2; ++q)
        __builtin_amdgcn_global_load_lds((const AS1 void*)(gstage + srcoff[q]),
                                         (AS3 void*)(lbase + q * 1024), 16, 0, 0);
    }

    const char* lb = (s & 1) ? lds1 : lds0;
    #pragma unroll
    for (int ct = 0; ct < 4; ++ct) {
      const int rloc = ct * 16 + p15;            // B row (col index n) in stage; rloc&15 == p15
      bf16x8 bfrag[4];
      #pragma unroll
      for (int ks = 0; ks < 4; ++ks)
        bfrag[ks] = *(const bf16x8*)(lb + rloc * 256 + (((rl4 + ks * 4) ^ p15) << 4));

      float tj = tsh[s * STAGE_COLS + ct * 16 + p15];  // quad-broadcast: conflict-free
      const bool pj = tj > 0.0f;
      const f32x4 tj4 = {tj, tj, tj, tj};
      const f32x4 K4  = {LOG2E, LOG2E, LOG2E, LOG2E};

      #pragma unroll
      for (int rs = 0; rs < 2; ++rs) {
        f32x4 acc = {0.f, 0.f, 0.f, 0.f};
        #pragma unroll
        for (int ks = 0; ks < 4; ++ks)
          acc = __builtin_amdgcn_mfma_f32_16x16x32_bf16(afrag[rs][ks], bfrag[ks], acc, 0, 0, 0);

        f32x4 c4 = acc;
        f32x4 d4 = ki[rs] - tj4;
        f32x4 m4;
        #pragma unroll
        for (int rr = 0; rr < 4; ++rr) {
          bool q = (__builtin_fabsf(d4[rr]) <= 0.1f) & ((ki[rs][rr] > 0.0f) == pj);
          m4[rr] = q ? 1.0f : 0.0f;
        }
        f32x4 x4 = c4 * K4 - K4;
        f32x4 e4;
        #pragma unroll
        for (int rr = 0; rr < 4; ++rr) e4[rr] = __builtin_amdgcn_exp2f(x4[rr]);
        Z[rs]  += e4;
        Zp[rs] += m4 * e4;
        Cp[rs] += m4 * c4;
        Np[rs] += m4;
      }
    }
  }

  // reduce over the 16 lanes (p15) sharing each row
  #pragma unroll
  for (int rs = 0; rs < 2; ++rs) {
    #pragma unroll
    for (int rr = 0; rr < 4; ++rr) {
      #pragma unroll
      for (int off = 1; off < 16; off <<= 1) {
        Z[rs][rr]  += __shfl_xor(Z[rs][rr],  off, 64);
        Zp[rs][rr] += __shfl_xor(Zp[rs][rr], off, 64);
        Cp[rs][rr] += __shfl_xor(Cp[rs][rr], off, 64);
        Np[rs][rr] += __shfl_xor(Np[rs][rr], off, 64);
      }
    }
  }
  if (p15 == 0) {
    #pragma unroll
    for (int rs = 0; rs < 2; ++rs)
      #pragma unroll
      for (int rr = 0; rr < 4; ++rr) {
        size_t row = rbase + rs * 16 + rl4 * 4 + rr;
        f32x4 st = {Z[rs][rr], Zp[rs][rr], Cp[rs][rr], Np[rs][rr]};
        *(f32x4*)&partials[((size_t)row * JCHUNKS + chunk) * 4] = st;
      }
  }
}

// ---------------- kernel 3: per-row loss + global mean (atomic) ----------------
__global__ void finalize_rows(const float* __restrict__ partials,
                              float* __restrict__ out) {
  int r = blockIdx.x * 256 + threadIdx.x;   // grid 32 x 256
  float Z = 0, Zp = 0, Cp = 0, Np = 0;
  for (int ch = 0; ch < JCHUNKS; ++ch) {
    float4 p = *(const float4*)&partials[((size_t)r * JCHUNKS + ch) * 4];
    Z += p.x; Zp += p.y; Cp += p.z; Np += p.w;
  }
  float Zn = Z - Zp;
  float nn = (float)NROWS - Np;
  float spos = (1.0f + logf(Z)) - Cp / Np;
  float sneg = Zn / Z - nn * 1e-10f;
  float per_row = spos + sneg / nn;

  float v = per_row;
  for (int off = 32; off; off >>= 1) v += __shfl_xor(v, off, 64);
  __shared__ float wsum[4];
  int lane = threadIdx.x & 63, wid = threadIdx.x >> 6;
  if (lane == 0) wsum[wid] = v;
  __syncthreads();
  if (threadIdx.x == 0)
    atomicAdd(out, (wsum[0] + wsum[1] + wsum[2] + wsum[3]) * (1.0f / (float)NROWS));
}

// ---------------- launch ----------------
extern "C" void kernel_launch(void* const* d_in, const int* in_sizes, int n_in,
                              void* d_out, int out_size, void* d_ws, size_t ws_size,
                              hipStream_t stream) {
  const float* f1  = (const float*)d_in[0];
  const float* f2  = (const float*)d_in[1];
  const float* tgt = (const float*)d_in[2];
  float* out = (float*)d_out;

  char* ws = (char*)d_ws;
  __hip_bfloat16* f1b = (__hip_bfloat16*)ws;                       // 2 MB
  __hip_bfloat16* f2b = (__hip_bfloat16*)(ws + (size_t)NROWS * DDIM * 2);
  float* partials = (float*)(ws + (size_t)NROWS * DDIM * 4);       // 2 MB

  norm_kernel<<<2 * (NROWS / 8), 256, 0, stream>>>(f1, f2, f1b, f2b, out);
  dim3 g2(GRIDX, JCHUNKS);
  stats_kernel<<<g2, 512, 0, stream>>>(f1b, f2b, tgt, partials);
  finalize_rows<<<NROWS / 256, 256, 0, stream>>>(partials, out);
}